// Round 5
// baseline (173.152 us; speedup 1.0000x reference)
//
#include <hip/hip_runtime.h>
#include <float.h>

#define TSEQ 4096
#define CEMB 1024
#define NH 64
#define WIN 256

typedef __attribute__((ext_vector_type(8))) short  s16x8;
typedef __attribute__((ext_vector_type(4))) float  f32x4;
typedef unsigned short ush;

// Truncation-based fp32 -> bf16 hi/lo split. |x - (hi+lo)| <= 2^-16 |x|.
__device__ __forceinline__ void split2(float f, ush& hi, ush& lo) {
    unsigned b = __float_as_uint(f);
    hi = (ush)(b >> 16);
    float hf = __uint_as_float(b & 0xFFFF0000u);
    lo = (ush)(__float_as_uint(f - hf) >> 16);
}

__device__ __forceinline__ void split8(f32x4 a, f32x4 b, s16x8& hi, s16x8& lo) {
    #pragma unroll
    for (int j = 0; j < 4; ++j) { ush h, l; split2(a[j], h, l); hi[j] = (short)h; lo[j] = (short)l; }
    #pragma unroll
    for (int j = 0; j < 4; ++j) { ush h, l; split2(b[j], h, l); hi[4+j] = (short)h; lo[4+j] = (short)l; }
}

#define MFMA(a, b, c) __builtin_amdgcn_mfma_f32_16x16x32_bf16((a), (b), (c), 0, 0, 0)

// ======================= W pre-convert: Wt[n][k] bf16 hi/lo =======================
__global__ __launch_bounds__(256)
void w_convert(const float* __restrict__ Wk, const float* __restrict__ Wq,
               const float* __restrict__ Wv,
               ush* __restrict__ Wth, ush* __restrict__ Wtl)
{
    const int m  = blockIdx.x >> 4;
    const int k0 = (blockIdx.x & 15) << 6;
    const float* src = (m == 0) ? Wk : ((m == 1) ? Wq : Wv);
    #pragma unroll
    for (int i = 0; i < 16; ++i) {
        const int idx = threadIdx.x + (i << 8);
        const int r = idx >> 6, c = idx & 63;
        const float v = src[(k0 + r) * NH + c];
        ush h, l; split2(v, h, l);
        const int o = (m * 64 + c) * CEMB + k0 + r;
        Wth[o] = h; Wtl[o] = l;
    }
}

// ======================= QKV projection via MFMA (M-tile 32, grid 512) =======================
__device__ __forceinline__ int swz(int row, int chunk) {
    return row * 32 + (((chunk) ^ ((row >> 1) & 3)) << 3);   // in shorts
}

__global__ __launch_bounds__(256)
void qkv_proj(const float* __restrict__ x,
              const ush* __restrict__ Wth, const ush* __restrict__ Wtl,
              ush* __restrict__ kbh, ush* __restrict__ kbl,
              ush* __restrict__ qbh, ush* __restrict__ qbl,
              ush* __restrict__ vbh, ush* __restrict__ vbl)
{
    __shared__ short Ah[2][32 * 32], Al[2][32 * 32];
    __shared__ short Bh[2][192 * 32], Bl[2][192 * 32];

    const int tid = threadIdx.x;
    const int m0  = blockIdx.x << 5;
    const int w   = tid >> 6;
    const int l15 = tid & 15;
    const int g   = (tid >> 4) & 3;

    // A staging: threads 0-127, one s16x8 chunk each
    const bool aact = tid < 128;
    const int arow  = tid >> 2;           // 0..31 when aact
    const int ach   = tid & 3;
    const float* xp = x + (size_t)(m0 + (aact ? arow : 0)) * CEMB + (ach << 3);

    // B staging: 768 chunks hi+lo, 3 each per thread
    int wn[3], wch[3];
    #pragma unroll
    for (int i = 0; i < 3; ++i) {
        const int c = tid + (i << 8);
        wn[i] = c >> 2; wch[i] = c & 3;
    }

    f32x4 acc[2][3];
    #pragma unroll
    for (int i = 0; i < 2; ++i)
        #pragma unroll
        for (int j = 0; j < 3; ++j) acc[i][j] = (f32x4){0.f, 0.f, 0.f, 0.f};

    f32x4 xr0 = {0,0,0,0}, xr1 = {0,0,0,0};
    if (aact) { xr0 = *(const f32x4*)(xp); xr1 = *(const f32x4*)(xp + 4); }
    s16x8 wrh[3], wrl[3];
    #pragma unroll
    for (int i = 0; i < 3; ++i) {
        const int o = wn[i] * CEMB + (wch[i] << 3);
        wrh[i] = *(const s16x8*)&Wth[o];
        wrl[i] = *(const s16x8*)&Wtl[o];
    }

    for (int t = 0; t < 32; ++t) {
        const int cur = t & 1;
        if (aact) {
            s16x8 vh, vl; split8(xr0, xr1, vh, vl);
            const int ao = swz(arow, ach);
            *(s16x8*)&Ah[cur][ao] = vh;
            *(s16x8*)&Al[cur][ao] = vl;
        }
        #pragma unroll
        for (int i = 0; i < 3; ++i) {
            const int bo = swz(wn[i], wch[i]);
            *(s16x8*)&Bh[cur][bo] = wrh[i];
            *(s16x8*)&Bl[cur][bo] = wrl[i];
        }
        __syncthreads();
        if (t < 31) {
            const int k0 = (t + 1) << 5;
            if (aact) { xr0 = *(const f32x4*)(xp + k0); xr1 = *(const f32x4*)(xp + k0 + 4); }
            #pragma unroll
            for (int i = 0; i < 3; ++i) {
                const int o = wn[i] * CEMB + k0 + (wch[i] << 3);
                wrh[i] = *(const s16x8*)&Wth[o];
                wrl[i] = *(const s16x8*)&Wtl[o];
            }
        }
        s16x8 afh[2], afl[2], bfh[3], bfl[3];
        #pragma unroll
        for (int rt = 0; rt < 2; ++rt) {
            const int o = swz(rt * 16 + l15, g);
            afh[rt] = *(const s16x8*)&Ah[cur][o];
            afl[rt] = *(const s16x8*)&Al[cur][o];
        }
        #pragma unroll
        for (int ct = 0; ct < 3; ++ct) {
            const int o = swz(w * 48 + ct * 16 + l15, g);
            bfh[ct] = *(const s16x8*)&Bh[cur][o];
            bfl[ct] = *(const s16x8*)&Bl[cur][o];
        }
        #pragma unroll
        for (int rt = 0; rt < 2; ++rt)
            #pragma unroll
            for (int ct = 0; ct < 3; ++ct) {
                acc[rt][ct] = MFMA(afh[rt], bfh[ct], acc[rt][ct]);
                acc[rt][ct] = MFMA(afh[rt], bfl[ct], acc[rt][ct]);
                acc[rt][ct] = MFMA(afl[rt], bfh[ct], acc[rt][ct]);
            }
    }

    // epilogue: store hi/lo shorts (C/D: row = g*4+r, col = l15 within 16-tile)
    #pragma unroll
    for (int ct = 0; ct < 3; ++ct) {
        const int colbase = w * 48 + ct * 16;
        ush* oph; ush* opl;
        if (colbase < 64)       { oph = kbh; opl = kbl; }
        else if (colbase < 128) { oph = qbh; opl = qbl; }
        else                    { oph = vbh; opl = vbl; }
        const int col = (colbase & 63) + l15;
        #pragma unroll
        for (int rt = 0; rt < 2; ++rt)
            #pragma unroll
            for (int r = 0; r < 4; ++r) {
                const size_t row = m0 + rt * 16 + g * 4 + r;
                ush h, l; split2(acc[rt][ct][r], h, l);
                oph[row * NH + col] = h;
                opl[row * NH + col] = l;
            }
    }
}

// ======================= V transpose: vbT[b][dim][T] =======================
__global__ __launch_bounds__(256)
void v_transpose(const ush* __restrict__ vbh, const ush* __restrict__ vbl,
                 ush* __restrict__ vbTh, ush* __restrict__ vbTl)
{
    const int k0  = blockIdx.x << 6;
    const int b   = blockIdx.y;
    const int dim = threadIdx.x & 63;
    const int j16 = threadIdx.x >> 6;
    const size_t inb = ((size_t)b * TSEQ + k0 + j16 * 16) * NH + dim;
    s16x8 h0, h1, l0, l1;
    #pragma unroll
    for (int j = 0; j < 8; ++j) {
        h0[j] = (short)vbh[inb + (size_t)j * NH];
        l0[j] = (short)vbl[inb + (size_t)j * NH];
    }
    #pragma unroll
    for (int j = 0; j < 8; ++j) {
        h1[j] = (short)vbh[inb + (size_t)(8 + j) * NH];
        l1[j] = (short)vbl[inb + (size_t)(8 + j) * NH];
    }
    const size_t ob = (size_t)b * (64 * TSEQ) + (size_t)dim * TSEQ + k0 + j16 * 16;
    *(s16x8*)&vbTh[ob]     = h0;
    *(s16x8*)&vbTh[ob + 8] = h1;
    *(s16x8*)&vbTl[ob]     = l0;
    *(s16x8*)&vbTl[ob + 8] = l1;
}

// ======================= Sliding-window attention, wave-split flash =======================
// Block: Q-tile 16, 4 independent waves splitting the window's K-tiles (stride 4).
// All K/Q/V fragments direct global->register. P via per-wave LDS (rotated chunks).
// Final: one barrier + cross-wave (m,l,O) combine in LDS.
__global__ __launch_bounds__(256)
void attn_swin(const ush* __restrict__ qbh, const ush* __restrict__ qbl,
               const ush* __restrict__ kbh, const ush* __restrict__ kbl,
               const ush* __restrict__ vbTh, const ush* __restrict__ vbTl,
               float* __restrict__ out)
{
    __shared__ ush Ph[4][16 * 64], Pl[4][16 * 64];
    __shared__ float cO[4][16][68];
    __shared__ float cm[4][16], cl[4][16];

    const int tid = threadIdx.x;
    const int w   = tid >> 6;
    const int l15 = tid & 15;
    const int g   = (tid >> 4) & 3;
    const int u   = l15 & 7;
    const int q0  = blockIdx.x << 4;
    const int b   = blockIdx.y;
    const size_t tbase = (size_t)b * TSEQ;
    const size_t vtb   = (size_t)b * (64 * TSEQ);

    const int qrow = q0 + l15;

    // Q B-fragments (col = qrow, k = dim = ks*32 + g*8 + i)
    s16x8 Qh[2], Ql[2];
    #pragma unroll
    for (int ks = 0; ks < 2; ++ks) {
        const size_t o = (tbase + qrow) * NH + ks * 32 + g * 8;
        Qh[ks] = *(const s16x8*)&qbh[o];
        Ql[ks] = *(const s16x8*)&qbl[o];
    }

    f32x4 O[4];
    #pragma unroll
    for (int i = 0; i < 4; ++i) O[i] = (f32x4){0.f, 0.f, 0.f, 0.f};
    float m_run = -FLT_MAX, l_run = 0.f;

    int lo = q0 - (WIN - 1); if (lo < 0) lo = 0;
    const int t_lo = lo >> 6, t_hi = q0 >> 6;

    for (int t = t_lo + w; t <= t_hi; t += 4) {
        const int k0 = t << 6;

        // ---- S^T = K*Q^T, K A-frags direct from global
        f32x4 S[4];
        #pragma unroll
        for (int kt = 0; kt < 4; ++kt) {
            f32x4 s = (f32x4){0.f, 0.f, 0.f, 0.f};
            #pragma unroll
            for (int ks = 0; ks < 2; ++ks) {
                const size_t o = (tbase + k0 + kt * 16 + l15) * NH + ks * 32 + g * 8;
                s16x8 kh = *(const s16x8*)&kbh[o];
                s16x8 kl = *(const s16x8*)&kbl[o];
                s = MFMA(kh, Qh[ks], s);
                s = MFMA(kh, Ql[ks], s);
                s = MFMA(kl, Qh[ks], s);
            }
            S[kt] = s;
        }

        // ---- mask + tile max (lane owns q-row l15; keys kt*16+g*4+r)
        float mt = -FLT_MAX;
        #pragma unroll
        for (int kt = 0; kt < 4; ++kt)
            #pragma unroll
            for (int r = 0; r < 4; ++r) {
                const int key = k0 + kt * 16 + g * 4 + r;
                const float s = S[kt][r] * 0.125f;
                S[kt][r] = s;
                if ((key <= qrow) && (key > qrow - WIN)) mt = fmaxf(mt, s);
            }
        mt = fmaxf(mt, __shfl_xor(mt, 16));
        mt = fmaxf(mt, __shfl_xor(mt, 32));
        const float mn  = fmaxf(m_run, mt);
        const float fsc = __expf(m_run - mn);

        // ---- P = exp(S-mn), masked; pack hi/lo into rotated LDS chunks
        float sum = 0.f;
        #pragma unroll
        for (int kt = 0; kt < 4; ++kt) {
            const int chunk = kt * 2 + (g >> 1);
            const int c2 = (chunk + u) & 7;
            const int abase = l15 * 64 + c2 * 8 + (g & 1) * 4;
            #pragma unroll
            for (int rp = 0; rp < 4; rp += 2) {
                const int key0 = k0 + kt * 16 + g * 4 + rp;
                const bool v0 = (key0     <= qrow) && (key0     > qrow - WIN);
                const bool v1 = (key0 + 1 <= qrow) && (key0 + 1 > qrow - WIN);
                const float p0 = v0 ? __expf(S[kt][rp]     - mn) : 0.f;
                const float p1 = v1 ? __expf(S[kt][rp + 1] - mn) : 0.f;
                sum += p0 + p1;
                ush h0, lo0, h1, lo1;
                split2(p0, h0, lo0); split2(p1, h1, lo1);
                *(unsigned int*)&Ph[w][abase + rp] = (unsigned int)h0  | ((unsigned int)h1  << 16);
                *(unsigned int*)&Pl[w][abase + rp] = (unsigned int)lo0 | ((unsigned int)lo1 << 16);
            }
        }
        sum += __shfl_xor(sum, 16);
        sum += __shfl_xor(sum, 32);
        l_run = l_run * fsc + sum;
        m_run = mn;

        // ---- rescale O (O rows g*4+r; factors live at lanes l15=row)
        float fr[4];
        #pragma unroll
        for (int r = 0; r < 4; ++r) fr[r] = __shfl(fsc, g * 4 + r);
        #pragma unroll
        for (int dt = 0; dt < 4; ++dt)
            #pragma unroll
            for (int r = 0; r < 4; ++r) O[dt][r] *= fr[r];

        // ---- O += P*V: A = P rows (LDS), B = V^T direct from global
        #pragma unroll
        for (int ks = 0; ks < 2; ++ks) {
            const int c2r = ((ks * 4 + g) + u) & 7;
            const int po = l15 * 64 + c2r * 8;
            s16x8 pah = *(const s16x8*)&Ph[w][po];
            s16x8 pal = *(const s16x8*)&Pl[w][po];
            #pragma unroll
            for (int dt = 0; dt < 4; ++dt) {
                const size_t vo = vtb + (size_t)(dt * 16 + l15) * TSEQ + k0 + ks * 32 + g * 8;
                s16x8 vh = *(const s16x8*)&vbTh[vo];
                s16x8 vl = *(const s16x8*)&vbTl[vo];
                O[dt] = MFMA(pah, vh, O[dt]);
                O[dt] = MFMA(pah, vl, O[dt]);
                O[dt] = MFMA(pal, vh, O[dt]);
            }
        }
    }

    // ---- cross-wave combine
    if (g == 0) { cm[w][l15] = m_run; cl[w][l15] = l_run; }
    #pragma unroll
    for (int dt = 0; dt < 4; ++dt)
        #pragma unroll
        for (int r = 0; r < 4; ++r)
            cO[w][g * 4 + r][dt * 16 + l15] = O[dt][r];
    __syncthreads();

    {
        const int dt = w;   // wave w finalizes dim-tile w
        #pragma unroll
        for (int r = 0; r < 4; ++r) {
            const int row = g * 4 + r;
            const float mm0 = cm[0][row], mm1 = cm[1][row], mm2 = cm[2][row], mm3 = cm[3][row];
            const float ms = fmaxf(fmaxf(mm0, mm1), fmaxf(mm2, mm3));
            const float f0 = __expf(mm0 - ms), f1 = __expf(mm1 - ms);
            const float f2 = __expf(mm2 - ms), f3 = __expf(mm3 - ms);
            const float ll = f0 * cl[0][row] + f1 * cl[1][row] + f2 * cl[2][row] + f3 * cl[3][row];
            const int col = dt * 16 + l15;
            const float oo = f0 * cO[0][row][col] + f1 * cO[1][row][col]
                           + f2 * cO[2][row][col] + f3 * cO[3][row][col];
            out[(tbase + q0 + row) * NH + col] = oo / ll;
        }
    }
}

extern "C" void kernel_launch(void* const* d_in, const int* in_sizes, int n_in,
                              void* d_out, int out_size, void* d_ws, size_t ws_size,
                              hipStream_t stream)
{
    const float* x  = (const float*)d_in[0];
    const float* Wk = (const float*)d_in[1];
    const float* Wq = (const float*)d_in[2];
    const float* Wv = (const float*)d_in[3];
    float* out = (float*)d_out;

    const int Bn = in_sizes[0] / (TSEQ * CEMB);
    const size_t perBuf = (size_t)Bn * TSEQ * NH;   // 1048576 shorts per buffer

    ush* base = (ush*)d_ws;
    ush* kbh = base;
    ush* kbl = kbh + perBuf;
    ush* qbh = kbl + perBuf;
    ush* qbl = qbh + perBuf;
    ush* vbh = qbl + perBuf;
    ush* vbl = vbh + perBuf;
    ush* vbTh = vbl + perBuf;
    ush* vbTl = vbTh + perBuf;
    ush* Wth = vbTl + perBuf;
    ush* Wtl = Wth + 192 * CEMB;

    w_convert<<<dim3(48), dim3(256), 0, stream>>>(Wk, Wq, Wv, Wth, Wtl);
    qkv_proj<<<dim3((Bn * TSEQ) / 32), dim3(256), 0, stream>>>(x, Wth, Wtl,
                                                               kbh, kbl, qbh, qbl, vbh, vbl);
    v_transpose<<<dim3(TSEQ / 64, Bn), dim3(256), 0, stream>>>(vbh, vbl, vbTh, vbTl);
    attn_swin<<<dim3(TSEQ / 16, Bn), dim3(256), 0, stream>>>(qbh, qbl, kbh, kbl,
                                                             vbTh, vbTl, out);
}

// Round 7
// 143.778 us; speedup vs baseline: 1.2043x; 1.2043x over previous
//
#include <hip/hip_runtime.h>
#include <float.h>

#define TSEQ 4096
#define CEMB 1024
#define NH 64
#define WIN 256

typedef __attribute__((ext_vector_type(8))) short  s16x8;
typedef __attribute__((ext_vector_type(4))) float  f32x4;
typedef unsigned short ush;

// Truncation-based fp32 -> bf16 hi/lo split. |x - (hi+lo)| <= 2^-16 |x|.
__device__ __forceinline__ void split2(float f, ush& hi, ush& lo) {
    unsigned b = __float_as_uint(f);
    hi = (ush)(b >> 16);
    float hf = __uint_as_float(b & 0xFFFF0000u);
    lo = (ush)(__float_as_uint(f - hf) >> 16);
}

__device__ __forceinline__ void split8(f32x4 a, f32x4 b, s16x8& hi, s16x8& lo) {
    #pragma unroll
    for (int j = 0; j < 4; ++j) { ush h, l; split2(a[j], h, l); hi[j] = (short)h; lo[j] = (short)l; }
    #pragma unroll
    for (int j = 0; j < 4; ++j) { ush h, l; split2(b[j], h, l); hi[4+j] = (short)h; lo[4+j] = (short)l; }
}

#define MFMA(a, b, c) __builtin_amdgcn_mfma_f32_16x16x32_bf16((a), (b), (c), 0, 0, 0)

// async global->LDS DMA, 16B per lane; lds base must be wave-uniform.
__device__ __forceinline__ void load_lds16(const void* g, void* l) {
    __builtin_amdgcn_global_load_lds(
        (const __attribute__((address_space(1))) unsigned int*)g,
        (__attribute__((address_space(3))) unsigned int*)l, 16, 0, 0);
}

// ============ W convert+transpose: W[1024][64] f32 -> Wt[n][k] bf16 hi/lo ============
// grid 48 = (16 k-tiles x 3 matrices), block 256. LDS tile transpose, vector IO.
__global__ __launch_bounds__(256)
void w_convert(const float* __restrict__ Wk, const float* __restrict__ Wq,
               const float* __restrict__ Wv,
               ush* __restrict__ Wth, ush* __restrict__ Wtl)
{
    __shared__ ush Lh[64][66], Ll[64][66];   // [n][k] within tile
    const int m  = blockIdx.x >> 4;
    const int k0 = (blockIdx.x & 15) << 6;
    const float* src = (m == 0) ? Wk : ((m == 1) ? Wq : Wv);

    const int kr = threadIdx.x >> 2;          // k-row 0..63
    const int cq = threadIdx.x & 3;           // col-quarter
    #pragma unroll
    for (int j = 0; j < 4; ++j) {
        const f32x4 v = *(const f32x4*)&src[(k0 + kr) * NH + cq * 16 + j * 4];
        #pragma unroll
        for (int e = 0; e < 4; ++e) {
            ush h, l; split2(v[e], h, l);
            const int c = cq * 16 + j * 4 + e;
            Lh[c][kr] = h; Ll[c][kr] = l;
        }
    }
    __syncthreads();
    const int n  = threadIdx.x >> 2;          // out col 0..63
    const int kc = threadIdx.x & 3;
    const size_t ob = (size_t)(m * 64 + n) * CEMB + k0 + kc * 16;
    *(s16x8*)&Wth[ob]     = *(const s16x8*)&Lh[n][kc * 16];
    *(s16x8*)&Wth[ob + 8] = *(const s16x8*)&Lh[n][kc * 16 + 8];
    *(s16x8*)&Wtl[ob]     = *(const s16x8*)&Ll[n][kc * 16];
    *(s16x8*)&Wtl[ob + 8] = *(const s16x8*)&Ll[n][kc * 16 + 8];
}

// ============ QKV projection: rows-32 tile, BK=64, x via swizzled-source DMA ============
// A LDS: fp32 [32 rows][16 slots of 4 floats], slot = chunk ^ (row&15) (2-way reads).
// B LDS: bf16 [192 n][8 slots of 8 shorts], slot = chunk ^ (n&7), single-buffered.
__global__ __launch_bounds__(256)
void qkv_proj(const float* __restrict__ x,
              const ush* __restrict__ Wth, const ush* __restrict__ Wtl,
              ush* __restrict__ kbh, ush* __restrict__ kbl,
              ush* __restrict__ qbh, ush* __restrict__ qbl,
              ush* __restrict__ vbh, ush* __restrict__ vbl)
{
    __shared__ float Axs[2][32 * 64];
    __shared__ ush  Bh[192 * 64], Bl[192 * 64];

    const int tid = threadIdx.x;
    const int m0  = blockIdx.x << 5;
    const int w   = tid >> 6;
    const int ln  = tid & 63;
    const int l15 = tid & 15;
    const int g   = (tid >> 4) & 3;

    // DMA lane mapping (2 issues/thread): dest slot d -> (row, slot); src chunk = slot^ (row&15)
    int dmr[2], dmc[2], dmbase[2];
    #pragma unroll
    for (int i = 0; i < 2; ++i) {
        const int d0 = w * 128 + i * 64;
        const int d  = d0 + ln;
        dmr[i] = d >> 4;
        dmc[i] = (d & 15) ^ (dmr[i] & 15);
        dmbase[i] = d0 * 4;                   // float index of wave-uniform base
    }

    // B staging: 6 slots/thread: s = tid + i*256 -> n = s>>3, chunk = s&7
    int bn[6], bc[6];
    #pragma unroll
    for (int i = 0; i < 6; ++i) {
        const int s = tid + (i << 8);
        bn[i] = s >> 3; bc[i] = s & 7;
    }

    f32x4 acc[2][3];
    #pragma unroll
    for (int i = 0; i < 2; ++i)
        #pragma unroll
        for (int j = 0; j < 3; ++j) acc[i][j] = (f32x4){0.f, 0.f, 0.f, 0.f};

    // prologue: DMA A(0), load W(0) regs
    #pragma unroll
    for (int i = 0; i < 2; ++i)
        load_lds16(&x[(size_t)(m0 + dmr[i]) * CEMB + dmc[i] * 4], &Axs[0][dmbase[i]]);
    s16x8 wrh[6], wrl[6];
    #pragma unroll
    for (int i = 0; i < 6; ++i) {
        const size_t o = (size_t)bn[i] * CEMB + bc[i] * 8;
        wrh[i] = *(const s16x8*)&Wth[o];
        wrl[i] = *(const s16x8*)&Wtl[o];
    }

    for (int t = 0; t < 16; ++t) {
        const int cur = t & 1;
        // write B(t) from prefetched regs (swizzled slots)
        #pragma unroll
        for (int i = 0; i < 6; ++i) {
            const int o = bn[i] * 64 + ((bc[i] ^ (bn[i] & 7)) << 3);
            *(s16x8*)&Bh[o] = wrh[i];
            *(s16x8*)&Bl[o] = wrl[i];
        }
        __syncthreads();   // B(t) visible; A(t) DMA drained (by this or previous barrier)

        if (t < 15) {
            #pragma unroll
            for (int i = 0; i < 2; ++i)
                load_lds16(&x[(size_t)(m0 + dmr[i]) * CEMB + (t + 1) * 64 + dmc[i] * 4],
                           &Axs[cur ^ 1][dmbase[i]]);
            #pragma unroll
            for (int i = 0; i < 6; ++i) {
                const size_t o = (size_t)bn[i] * CEMB + (t + 1) * 64 + bc[i] * 8;
                wrh[i] = *(const s16x8*)&Wth[o];
                wrl[i] = *(const s16x8*)&Wtl[o];
            }
        }

        // compute on Axs[cur] + B
        #pragma unroll
        for (int ks = 0; ks < 2; ++ks) {
            s16x8 afh[2], afl[2], bfh[3], bfl[3];
            #pragma unroll
            for (int rt = 0; rt < 2; ++rt) {
                const int row = rt * 16 + l15;
                const int c0 = ks * 8 + g * 2;
                const f32x4 a0 = *(const f32x4*)&Axs[cur][row * 64 + ((c0     ^ l15) << 2)];
                const f32x4 a1 = *(const f32x4*)&Axs[cur][row * 64 + (((c0+1) ^ l15) << 2)];
                split8(a0, a1, afh[rt], afl[rt]);
            }
            #pragma unroll
            for (int ct = 0; ct < 3; ++ct) {
                const int n = w * 48 + ct * 16 + l15;
                const int o = n * 64 + (((ks * 4 + g) ^ (n & 7)) << 3);
                bfh[ct] = *(const s16x8*)&Bh[o];
                bfl[ct] = *(const s16x8*)&Bl[o];
            }
            __builtin_amdgcn_s_setprio(1);
            #pragma unroll
            for (int rt = 0; rt < 2; ++rt)
                #pragma unroll
                for (int ct = 0; ct < 3; ++ct) {
                    acc[rt][ct] = MFMA(afh[rt], bfh[ct], acc[rt][ct]);
                    acc[rt][ct] = MFMA(afh[rt], bfl[ct], acc[rt][ct]);
                    acc[rt][ct] = MFMA(afl[rt], bfh[ct], acc[rt][ct]);
                }
            __builtin_amdgcn_s_setprio(0);
        }
        __syncthreads();   // all reads of B(t)/A(t) done before next overwrite
    }

    // epilogue: C/D row = g*4+r, col = l15; store bf16 hi/lo
    #pragma unroll
    for (int ct = 0; ct < 3; ++ct) {
        const int colbase = w * 48 + ct * 16;
        ush *oph, *opl;
        if (colbase < 64)       { oph = kbh; opl = kbl; }
        else if (colbase < 128) { oph = qbh; opl = qbl; }
        else                    { oph = vbh; opl = vbl; }
        const int col = (colbase & 63) + l15;
        #pragma unroll
        for (int rt = 0; rt < 2; ++rt)
            #pragma unroll
            for (int r = 0; r < 4; ++r) {
                const size_t row = m0 + rt * 16 + g * 4 + r;
                ush h, l; split2(acc[rt][ct][r], h, l);
                oph[row * NH + col] = h;
                opl[row * NH + col] = l;
            }
    }
}

// ============ V transpose: vb[b*T][64] -> vbT[(b*64+dim)][T], LDS tile transpose ============
__global__ __launch_bounds__(256)
void v_transpose(const ush* __restrict__ vbh, const ush* __restrict__ vbl,
                 ush* __restrict__ vbTh, ush* __restrict__ vbTl)
{
    __shared__ ush Th[64][72], Tl[64][72];    // [dim][key]
    const int k0 = blockIdx.x << 6;
    const int b  = blockIdx.y;
    const int key = threadIdx.x >> 2;
    const int cp  = (threadIdx.x & 3) << 1;   // chunk pair
    #pragma unroll
    for (int i = 0; i < 2; ++i) {
        const int c = cp + i;
        const size_t o = ((size_t)b * TSEQ + k0 + key) * NH + c * 8;
        const s16x8 h = *(const s16x8*)&vbh[o];
        const s16x8 l = *(const s16x8*)&vbl[o];
        #pragma unroll
        for (int j = 0; j < 8; ++j) {
            Th[c * 8 + j][key] = (ush)h[j];
            Tl[c * 8 + j][key] = (ush)l[j];
        }
    }
    __syncthreads();
    const int dim = threadIdx.x >> 2;
    const int kc  = threadIdx.x & 3;
    const size_t ob = ((size_t)b * 64 + dim) * TSEQ + k0 + kc * 16;
    *(s16x8*)&vbTh[ob]     = *(const s16x8*)&Th[dim][kc * 16];
    *(s16x8*)&vbTh[ob + 8] = *(const s16x8*)&Th[dim][kc * 16 + 8];
    *(s16x8*)&vbTl[ob]     = *(const s16x8*)&Tl[dim][kc * 16];
    *(s16x8*)&vbTl[ob + 8] = *(const s16x8*)&Tl[dim][kc * 16 + 8];
}

// ============ Sliding-window attention: Q-tile 64, staged K/V^T, swapped-QK MFMA ============
__global__ __launch_bounds__(256)
void attn_swin(const ush* __restrict__ qbh, const ush* __restrict__ qbl,
               const ush* __restrict__ kbh, const ush* __restrict__ kbl,
               const ush* __restrict__ vbTh, const ush* __restrict__ vbTl,
               float* __restrict__ out)
{
    __shared__ ush Kh[64 * 72], Kl[64 * 72];      // [key][dim]
    __shared__ ush Vth[64 * 72], Vtl[64 * 72];    // [dim][key]
    __shared__ ush Ph[4][16 * 64], Pl[4][16 * 64];

    const int tid = threadIdx.x;
    const int q0  = blockIdx.x << 6;
    const int b   = blockIdx.y;
    const size_t tb  = (size_t)b * TSEQ;
    const size_t vtb = (size_t)b * 64;
    const int w   = tid >> 6;
    const int l15 = tid & 15;
    const int g   = (tid >> 4) & 3;
    const int u   = l15 & 7;

    const int qrow = q0 + w * 16 + l15;

    s16x8 Qh[2], Ql[2];
    #pragma unroll
    for (int ks = 0; ks < 2; ++ks) {
        const size_t o = (tb + qrow) * NH + ks * 32 + g * 8;
        Qh[ks] = *(const s16x8*)&qbh[o];
        Ql[ks] = *(const s16x8*)&qbl[o];
    }

    f32x4 O[4];
    #pragma unroll
    for (int i = 0; i < 4; ++i) O[i] = (f32x4){0.f, 0.f, 0.f, 0.f};
    float m_run = -FLT_MAX, l_run = 0.f;

    int lo = q0 - (WIN - 1); if (lo < 0) lo = 0;
    const int t_lo = lo >> 6, t_hi = q0 >> 6;

    const int skey = tid >> 2;              // staging row (key or dim)
    const int scp  = (tid & 3) << 1;        // staging chunk pair

    for (int t = t_lo; t <= t_hi; ++t) {
        const int k0 = t << 6;
        __syncthreads();      // previous tile's readers done
        #pragma unroll
        for (int i = 0; i < 2; ++i) {
            const int c = scp + i;
            const size_t ko = (tb + k0 + skey) * NH + c * 8;
            const size_t vo = (vtb + skey) * TSEQ + k0 + c * 8;
            *(s16x8*)&Kh[skey * 72 + c * 8]  = *(const s16x8*)&kbh[ko];
            *(s16x8*)&Kl[skey * 72 + c * 8]  = *(const s16x8*)&kbl[ko];
            *(s16x8*)&Vth[skey * 72 + c * 8] = *(const s16x8*)&vbTh[vo];
            *(s16x8*)&Vtl[skey * 72 + c * 8] = *(const s16x8*)&vbTl[vo];
        }
        __syncthreads();

        // ---- S^T = K * Q^T
        f32x4 S[4];
        __builtin_amdgcn_s_setprio(1);
        #pragma unroll
        for (int kt = 0; kt < 4; ++kt) {
            f32x4 s = (f32x4){0.f, 0.f, 0.f, 0.f};
            #pragma unroll
            for (int ks = 0; ks < 2; ++ks) {
                const int o = (kt * 16 + l15) * 72 + ks * 32 + g * 8;
                const s16x8 kah = *(const s16x8*)&Kh[o];
                const s16x8 kal = *(const s16x8*)&Kl[o];
                s = MFMA(kah, Qh[ks], s);
                s = MFMA(kah, Ql[ks], s);
                s = MFMA(kal, Qh[ks], s);
            }
            S[kt] = s;
        }
        __builtin_amdgcn_s_setprio(0);

        // ---- mask + online softmax (lane owns q-row l15 of wave w)
        float mt = -FLT_MAX;
        #pragma unroll
        for (int kt = 0; kt < 4; ++kt)
            #pragma unroll
            for (int r = 0; r < 4; ++r) {
                const int key = k0 + kt * 16 + g * 4 + r;
                const float s = S[kt][r] * 0.125f;
                S[kt][r] = s;
                if ((key <= qrow) && (key > qrow - WIN)) mt = fmaxf(mt, s);
            }
        mt = fmaxf(mt, __shfl_xor(mt, 16));
        mt = fmaxf(mt, __shfl_xor(mt, 32));
        const float mn  = fmaxf(m_run, mt);
        const float fsc = __expf(m_run - mn);

        float sum = 0.f;
        #pragma unroll
        for (int kt = 0; kt < 4; ++kt) {
            const int c2 = ((kt * 2 + (g >> 1)) + u) & 7;
            const int abase = l15 * 64 + c2 * 8 + (g & 1) * 4;
            #pragma unroll
            for (int rp = 0; rp < 4; rp += 2) {
                const int key0 = k0 + kt * 16 + g * 4 + rp;
                const bool v0 = (key0     <= qrow) && (key0     > qrow - WIN);
                const bool v1 = (key0 + 1 <= qrow) && (key0 + 1 > qrow - WIN);
                const float p0 = v0 ? __expf(S[kt][rp]     - mn) : 0.f;
                const float p1 = v1 ? __expf(S[kt][rp + 1] - mn) : 0.f;
                sum += p0 + p1;
                ush h0, lo0, h1, lo1;
                split2(p0, h0, lo0); split2(p1, h1, lo1);
                *(unsigned int*)&Ph[w][abase + rp] = (unsigned int)h0  | ((unsigned int)h1  << 16);
                *(unsigned int*)&Pl[w][abase + rp] = (unsigned int)lo0 | ((unsigned int)lo1 << 16);
            }
        }
        sum += __shfl_xor(sum, 16);
        sum += __shfl_xor(sum, 32);
        l_run = l_run * fsc + sum;
        m_run = mn;

        float fr[4];
        #pragma unroll
        for (int r = 0; r < 4; ++r) fr[r] = __shfl(fsc, g * 4 + r);
        #pragma unroll
        for (int dt = 0; dt < 4; ++dt)
            #pragma unroll
            for (int r = 0; r < 4; ++r) O[dt][r] *= fr[r];

        // ---- O += P * V (A = P rows, B = V^T rows from LDS)
        #pragma unroll
        for (int ks = 0; ks < 2; ++ks) {
            const int po = l15 * 64 + ((((ks * 4 + g)) + u) & 7) * 8;
            const s16x8 pah = *(const s16x8*)&Ph[w][po];
            const s16x8 pal = *(const s16x8*)&Pl[w][po];
            __builtin_amdgcn_s_setprio(1);
            #pragma unroll
            for (int dt = 0; dt < 4; ++dt) {
                const int vo = (dt * 16 + l15) * 72 + ks * 32 + g * 8;
                const s16x8 vbh8 = *(const s16x8*)&Vth[vo];
                const s16x8 vbl8 = *(const s16x8*)&Vtl[vo];
                O[dt] = MFMA(pah, vbh8, O[dt]);
                O[dt] = MFMA(pah, vbl8, O[dt]);
                O[dt] = MFMA(pal, vbh8, O[dt]);
            }
            __builtin_amdgcn_s_setprio(0);
        }
    }

    const float linv = 1.f / l_run;
    float fr[4];
    #pragma unroll
    for (int r = 0; r < 4; ++r) fr[r] = __shfl(linv, g * 4 + r);
    #pragma unroll
    for (int dt = 0; dt < 4; ++dt)
        #pragma unroll
        for (int r = 0; r < 4; ++r) {
            const int row = q0 + w * 16 + g * 4 + r;
            out[(tb + row) * NH + dt * 16 + l15] = O[dt][r] * fr[r];
        }
}

extern "C" void kernel_launch(void* const* d_in, const int* in_sizes, int n_in,
                              void* d_out, int out_size, void* d_ws, size_t ws_size,
                              hipStream_t stream)
{
    const float* x  = (const float*)d_in[0];
    const float* Wk = (const float*)d_in[1];
    const float* Wq = (const float*)d_in[2];
    const float* Wv = (const float*)d_in[3];
    float* out = (float*)d_out;

    const int Bn = in_sizes[0] / (TSEQ * CEMB);
    const size_t perBuf = (size_t)Bn * TSEQ * NH;

    ush* base = (ush*)d_ws;
    ush* kbh = base;
    ush* kbl = kbh + perBuf;
    ush* qbh = kbl + perBuf;
    ush* qbl = qbh + perBuf;
    ush* vbh = qbl + perBuf;
    ush* vbl = vbh + perBuf;
    ush* vbTh = vbl + perBuf;
    ush* vbTl = vbTh + perBuf;
    ush* Wth = vbTl + perBuf;
    ush* Wtl = Wth + 192 * CEMB;

    w_convert<<<dim3(48), dim3(256), 0, stream>>>(Wk, Wq, Wv, Wth, Wtl);
    qkv_proj<<<dim3((Bn * TSEQ) / 32), dim3(256), 0, stream>>>(x, Wth, Wtl,
                                                               kbh, kbl, qbh, qbl, vbh, vbl);
    v_transpose<<<dim3(TSEQ / 64, Bn), dim3(256), 0, stream>>>(vbh, vbl, vbTh, vbTl);
    attn_swin<<<dim3(TSEQ / 64, Bn), dim3(256), 0, stream>>>(qbh, qbl, kbh, kbl,
                                                             vbTh, vbTl, out);
}